// Round 1
// baseline (75.519 us; speedup 1.0000x reference)
//
#include <hip/hip_runtime.h>
#include <math.h>

#define N_KEYS 8192
#define DIM    1024
#define BQ     64
#define TOPK   4
#define HD     512      // d/2
#define KC     128      // K-dim chunk staged in LDS
#define SQ     132      // padded LDS row stride (floats): 528B rows, 16B-aligned

// ---------------- Kernel 1: eq = exp(q) ----------------
__global__ __launch_bounds__(256) void expq_kernel(const float* __restrict__ q,
                                                   float* __restrict__ eq) {
    int i = blockIdx.x * 256 + threadIdx.x;   // grid sized exactly to BQ*DIM
    eq[i] = expf(q[i]);
}

// ---------------- Kernel 2: scores = log(exp(Q) @ exp(K)^T) ----------------
// grid = N_KEYS/32 blocks, 256 threads. Tile: 64 (all B) x 32 keys.
__global__ __launch_bounds__(256) void scores_kernel(const float* __restrict__ eq,
                                                     const float* __restrict__ keys,
                                                     float* __restrict__ scores) {
    __shared__ float qs[BQ * SQ];   // 64 x 132 floats = 33 KB
    __shared__ float ks[32 * SQ];   // 32 x 132 floats = 16.5 KB

    const int t  = threadIdx.x;
    const int ty = t >> 3;    // 0..31  -> b rows {ty, ty+32}
    const int tx = t & 7;     // 0..7   -> key rows {tx, tx+8, tx+16, tx+24}
    const int i0 = blockIdx.x * 32;

    const float4* eq4 = (const float4*)eq;    // row stride 256 float4
    const float4* k4  = (const float4*)keys;  // row stride 256 float4

    float acc[2][4] = {{0.f,0.f,0.f,0.f},{0.f,0.f,0.f,0.f}};

    for (int c = 0; c < DIM / KC; ++c) {
        // ---- stage Q chunk: 64x128 floats = 2048 float4, 8 per thread ----
        #pragma unroll
        for (int r = 0; r < 8; ++r) {
            int l   = t + 256 * r;        // 0..2047
            int row = l >> 5;             // 0..63
            int c4  = l & 31;             // 0..31
            float4 v = eq4[row * 256 + c * 32 + c4];
            *(float4*)&qs[row * SQ + c4 * 4] = v;
        }
        // ---- stage K chunk (exp on the fly): 32x128 = 1024 float4, 4/thread ----
        #pragma unroll
        for (int r = 0; r < 4; ++r) {
            int l   = t + 256 * r;        // 0..1023
            int row = l >> 5;             // 0..31
            int c4  = l & 31;
            float4 v = k4[(size_t)(i0 + row) * 256 + c * 32 + c4];
            float4 e;
            e.x = expf(v.x); e.y = expf(v.y); e.z = expf(v.z); e.w = expf(v.w);
            *(float4*)&ks[row * SQ + c4 * 4] = e;
        }
        __syncthreads();

        const float* qa  = qs + ty * SQ;
        const float* qb  = qs + (ty + 32) * SQ;
        const float* kb0 = ks + tx * SQ;
        const float* kb1 = ks + (tx + 8) * SQ;
        const float* kb2 = ks + (tx + 16) * SQ;
        const float* kb3 = ks + (tx + 24) * SQ;

        #pragma unroll 8
        for (int kk = 0; kk < KC; kk += 4) {
            float4 A0 = *(const float4*)(qa  + kk);
            float4 A1 = *(const float4*)(qb  + kk);
            float4 B0 = *(const float4*)(kb0 + kk);
            float4 B1 = *(const float4*)(kb1 + kk);
            float4 B2 = *(const float4*)(kb2 + kk);
            float4 B3 = *(const float4*)(kb3 + kk);

            acc[0][0] += A0.x*B0.x + A0.y*B0.y + A0.z*B0.z + A0.w*B0.w;
            acc[0][1] += A0.x*B1.x + A0.y*B1.y + A0.z*B1.z + A0.w*B1.w;
            acc[0][2] += A0.x*B2.x + A0.y*B2.y + A0.z*B2.z + A0.w*B2.w;
            acc[0][3] += A0.x*B3.x + A0.y*B3.y + A0.z*B3.z + A0.w*B3.w;
            acc[1][0] += A1.x*B0.x + A1.y*B0.y + A1.z*B0.z + A1.w*B0.w;
            acc[1][1] += A1.x*B1.x + A1.y*B1.y + A1.z*B1.z + A1.w*B1.w;
            acc[1][2] += A1.x*B2.x + A1.y*B2.y + A1.z*B2.z + A1.w*B2.w;
            acc[1][3] += A1.x*B3.x + A1.y*B3.y + A1.z*B3.z + A1.w*B3.w;
        }
        __syncthreads();
    }

    #pragma unroll
    for (int s2 = 0; s2 < 2; ++s2) {
        #pragma unroll
        for (int r = 0; r < 4; ++r) {
            int b = ty + 32 * s2;
            int i = i0 + tx + 8 * r;
            scores[(size_t)b * N_KEYS + i] = logf(acc[s2][r]);
        }
    }
}

// ---------------- Kernel 3: top-k + softmax + gather ----------------
__device__ __forceinline__ bool better(float a, int ai, float b, int bi) {
    return (a > b) || (a == b && ai < bi);
}

__global__ __launch_bounds__(256) void topk_kernel(const float* __restrict__ scores,
                                                   const float* __restrict__ theta,
                                                   const float* __restrict__ mag,
                                                   float* __restrict__ out) {
    const int b = blockIdx.x;
    const int t = threadIdx.x;

    __shared__ float cs[1024];
    __shared__ int   ci[1024];
    __shared__ float rv[256];
    __shared__ int   ri[256];
    __shared__ int   rp[256];
    __shared__ float topv[TOPK];
    __shared__ int   topis[TOPK];
    __shared__ float wv[TOPK];

    // per-thread sorted top-4 over a strided scan
    float tv[4]  = {-INFINITY, -INFINITY, -INFINITY, -INFINITY};
    int   tix[4] = {0x7fffffff, 0x7fffffff, 0x7fffffff, 0x7fffffff};
    const float* srow = scores + (size_t)b * N_KEYS;
    for (int i = t; i < N_KEYS; i += 256) {
        float s = srow[i];
        if (better(s, i, tv[3], tix[3])) {
            tv[3] = s; tix[3] = i;
            #pragma unroll
            for (int p = 3; p > 0; --p) {
                if (better(tv[p], tix[p], tv[p - 1], tix[p - 1])) {
                    float fv = tv[p]; tv[p] = tv[p-1]; tv[p-1] = fv;
                    int   fi = tix[p]; tix[p] = tix[p-1]; tix[p-1] = fi;
                }
            }
        }
    }
    #pragma unroll
    for (int e = 0; e < 4; ++e) { cs[t * 4 + e] = tv[e]; ci[t * 4 + e] = tix[e]; }
    __syncthreads();

    // 4 rounds of global argmax over the 1024-candidate pool
    for (int round = 0; round < TOPK; ++round) {
        float bv = -INFINITY; int bi = 0x7fffffff; int bp = -1;
        #pragma unroll
        for (int e = 0; e < 4; ++e) {
            int p = t * 4 + e;
            if (better(cs[p], ci[p], bv, bi)) { bv = cs[p]; bi = ci[p]; bp = p; }
        }
        rv[t] = bv; ri[t] = bi; rp[t] = bp;
        __syncthreads();
        for (int s = 128; s > 0; s >>= 1) {
            if (t < s) {
                if (better(rv[t + s], ri[t + s], rv[t], ri[t])) {
                    rv[t] = rv[t + s]; ri[t] = ri[t + s]; rp[t] = rp[t + s];
                }
            }
            __syncthreads();
        }
        if (t == 0) {
            topv[round] = rv[0]; topis[round] = ri[0];
            cs[rp[0]] = -INFINITY;   // remove winner from pool
        }
        __syncthreads();
    }

    // softmax over the 4 selected scores (descending order, like jax top_k)
    if (t == 0) {
        float m = topv[0];
        float e0 = expf(topv[0] - m), e1 = expf(topv[1] - m),
              e2 = expf(topv[2] - m), e3 = expf(topv[3] - m);
        float s = e0 + e1 + e2 + e3;
        wv[0] = e0 / s; wv[1] = e1 / s; wv[2] = e2 / s; wv[3] = e3 / s;
    }
    __syncthreads();

    // gather theta rows: 4 x 512 floats = 512 float4
    const float4* th4 = (const float4*)theta;
    float4* out4 = (float4*)out;
    for (int l = t; l < TOPK * (HD / 4); l += 256) {
        int j  = l >> 7;          // 0..3
        int c4 = l & 127;         // 0..127
        out4[((size_t)b * TOPK + j) * (HD / 4) + c4] =
            th4[(size_t)topis[j] * (HD / 4) + c4];
    }
    // mag and w
    if (t < TOPK) {
        out[(size_t)BQ * TOPK * HD + b * TOPK + t]             = mag[topis[t]];
        out[(size_t)BQ * TOPK * HD + BQ * TOPK + b * TOPK + t] = wv[t];
    }
}

extern "C" void kernel_launch(void* const* d_in, const int* in_sizes, int n_in,
                              void* d_out, int out_size, void* d_ws, size_t ws_size,
                              hipStream_t stream) {
    const float* q     = (const float*)d_in[0];
    const float* keys  = (const float*)d_in[1];
    const float* theta = (const float*)d_in[2];
    const float* mag   = (const float*)d_in[3];
    float* out = (float*)d_out;

    float* eq     = (float*)d_ws;                 // BQ*DIM floats
    float* scores = eq + (size_t)BQ * DIM;        // BQ*N_KEYS floats

    expq_kernel<<<(BQ * DIM) / 256, 256, 0, stream>>>(q, eq);
    scores_kernel<<<N_KEYS / 32, 256, 0, stream>>>(eq, keys, scores);
    topk_kernel<<<BQ, 256, 0, stream>>>(scores, theta, mag, out);
}

// Round 2
// 56.732 us; speedup vs baseline: 1.3312x; 1.3312x over previous
//
#include <hip/hip_runtime.h>
#include <math.h>

#define N_KEYS 8192
#define DIM    1024
#define BQ     64
#define TOPK   4
#define HD     512
#define LS     68            // LDS row stride (floats): 272B, 16B-aligned, odd mod-8 in float4 groups

__device__ __forceinline__ bool better(float av, int ai, float bv, int bi) {
    return (av > bv) || (av == bv && ai < bi);
}

// compare-exchange: ensure (av,ai) is the better one
__device__ __forceinline__ void ce(float& av, int& ai, float& bv, int& bi) {
    if (!better(av, ai, bv, bi)) {
        float tv = av; av = bv; bv = tv;
        int   ti = ai; ai = bi; bi = ti;
    }
}

// merge own sorted-desc top-4 with lane^off partner's via bitonic 4-merge
__device__ __forceinline__ void merge_shfl(float v[4], int ix[4], int off) {
    float pv[4]; int pi[4];
    #pragma unroll
    for (int r = 0; r < 4; ++r) {
        pv[r] = __shfl_xor(v[r], off);
        pi[r] = __shfl_xor(ix[r], off);
    }
    float nv[4]; int ni[4];
    #pragma unroll
    for (int r = 0; r < 4; ++r) {
        bool ta = better(v[r], ix[r], pv[3 - r], pi[3 - r]);
        nv[r] = ta ? v[r]  : pv[3 - r];
        ni[r] = ta ? ix[r] : pi[3 - r];
    }
    ce(nv[0], ni[0], nv[2], ni[2]);
    ce(nv[1], ni[1], nv[3], ni[3]);
    ce(nv[0], ni[0], nv[1], ni[1]);
    ce(nv[2], ni[2], nv[3], ni[3]);
    #pragma unroll
    for (int r = 0; r < 4; ++r) { v[r] = nv[r]; ix[r] = ni[r]; }
}

// ---------------- scores: part[y][b][i] = sum_{d in slice y} exp(q[b,d])*exp(k[i,d]) ----
template<int KSPLIT>
__global__ __launch_bounds__(256) void scores_kernel(const float* __restrict__ q,
                                                     const float* __restrict__ keys,
                                                     float* __restrict__ part) {
    constexpr int DPB = DIM / KSPLIT;      // dims per block
    __shared__ float qs[BQ * LS];          // 64 x 64 chunk, stride 68
    __shared__ float ks[64 * LS];

    const int t  = threadIdx.x;
    const int tx = t & 15;                 // key rows {tx+16n}
    const int ty = t >> 4;                 // b rows  {ty+16m}
    const int i0 = blockIdx.x * 64;
    const int d0 = blockIdx.y * DPB;

    const float4* q4 = (const float4*)q;   // row stride 256 float4
    const float4* k4 = (const float4*)keys;

    float acc[4][4] = {};

    for (int c = 0; c < DPB / 64; ++c) {
        const int dc4 = (d0 >> 2) + c * 16;
        // stage exp(Q) chunk: 64x64 floats = 1024 float4, 4/thread
        #pragma unroll
        for (int r = 0; r < 4; ++r) {
            int l = t + 256 * r, row = l >> 4, c4 = l & 15;
            float4 v = q4[row * 256 + dc4 + c4];
            float4 e = make_float4(expf(v.x), expf(v.y), expf(v.z), expf(v.w));
            *(float4*)&qs[row * LS + c4 * 4] = e;
        }
        // stage exp(K) chunk
        #pragma unroll
        for (int r = 0; r < 4; ++r) {
            int l = t + 256 * r, row = l >> 4, c4 = l & 15;
            float4 v = k4[(size_t)(i0 + row) * 256 + dc4 + c4];
            float4 e = make_float4(expf(v.x), expf(v.y), expf(v.z), expf(v.w));
            *(float4*)&ks[row * LS + c4 * 4] = e;
        }
        __syncthreads();

        #pragma unroll
        for (int kk = 0; kk < 64; kk += 4) {
            float4 av[4], bv[4];
            #pragma unroll
            for (int m = 0; m < 4; ++m) av[m] = *(const float4*)&qs[(ty + 16 * m) * LS + kk];
            #pragma unroll
            for (int n = 0; n < 4; ++n) bv[n] = *(const float4*)&ks[(tx + 16 * n) * LS + kk];
            #pragma unroll
            for (int m = 0; m < 4; ++m)
                #pragma unroll
                for (int n = 0; n < 4; ++n)
                    acc[m][n] += av[m].x * bv[n].x + av[m].y * bv[n].y
                               + av[m].z * bv[n].z + av[m].w * bv[n].w;
        }
        __syncthreads();
    }

    float* pb = part + (size_t)blockIdx.y * (BQ * N_KEYS);
    #pragma unroll
    for (int m = 0; m < 4; ++m)
        #pragma unroll
        for (int n = 0; n < 4; ++n)
            pb[(size_t)(ty + 16 * m) * N_KEYS + i0 + tx + 16 * n] = acc[m][n];
}

// ---------------- topk partial: per (b, quarter-of-keys) sorted top-4 ----------------
template<int KSPLIT>
__global__ __launch_bounds__(1024) void topk_partial(const float* __restrict__ part,
                                                     float* __restrict__ cv,
                                                     int* __restrict__ ci) {
    const int b     = blockIdx.x >> 2;
    const int chunk = blockIdx.x & 3;
    const int t     = threadIdx.x;
    const int lane  = t & 63, wid = t >> 6;

    __shared__ float sv[16][4];
    __shared__ int   si[16][4];

    float v[4]  = {-INFINITY, -INFINITY, -INFINITY, -INFINITY};
    int   ix[4] = {0x7fffffff, 0x7fffffff, 0x7fffffff, 0x7fffffff};

    const float* pb = part + (size_t)b * N_KEYS;
    #pragma unroll
    for (int r = 0; r < 2; ++r) {
        int i = chunk * 2048 + t + r * 1024;
        float s = 0.f;
        #pragma unroll
        for (int sl = 0; sl < KSPLIT; ++sl)
            s += pb[(size_t)sl * (BQ * N_KEYS) + i];
        if (better(s, i, v[3], ix[3])) {
            v[3] = s; ix[3] = i;
            #pragma unroll
            for (int p = 3; p > 0; --p) {
                if (better(v[p], ix[p], v[p - 1], ix[p - 1])) {
                    float tv = v[p]; v[p] = v[p-1]; v[p-1] = tv;
                    int   ti = ix[p]; ix[p] = ix[p-1]; ix[p-1] = ti;
                }
            }
        }
    }
    merge_shfl(v, ix, 1);  merge_shfl(v, ix, 2);  merge_shfl(v, ix, 4);
    merge_shfl(v, ix, 8);  merge_shfl(v, ix, 16); merge_shfl(v, ix, 32);

    if (lane == 0) {
        #pragma unroll
        for (int r = 0; r < 4; ++r) { sv[wid][r] = v[r]; si[wid][r] = ix[r]; }
    }
    __syncthreads();

    if (wid == 0) {
        float mv[4]; int mi[4];
        if (lane < 16) {
            #pragma unroll
            for (int r = 0; r < 4; ++r) { mv[r] = sv[lane][r]; mi[r] = si[lane][r]; }
        } else {
            #pragma unroll
            for (int r = 0; r < 4; ++r) { mv[r] = -INFINITY; mi[r] = 0x7fffffff; }
        }
        merge_shfl(mv, mi, 1); merge_shfl(mv, mi, 2);
        merge_shfl(mv, mi, 4); merge_shfl(mv, mi, 8);
        if (lane == 0) {
            #pragma unroll
            for (int r = 0; r < 4; ++r) {
                cv[blockIdx.x * 4 + r] = mv[r];
                ci[blockIdx.x * 4 + r] = mi[r];
            }
        }
    }
}

// ---------------- finalize: merge 4 chunk-lists, softmax, gather ----------------
__global__ __launch_bounds__(64) void finalize_kernel(const float* __restrict__ cv,
                                                      const int* __restrict__ ci,
                                                      const float* __restrict__ theta,
                                                      const float* __restrict__ mag,
                                                      float* __restrict__ out) {
    const int b    = blockIdx.x;
    const int lane = threadIdx.x;   // 64

    __shared__ float fw[4];
    __shared__ int   fi[4];

    float v[4]  = {-INFINITY, -INFINITY, -INFINITY, -INFINITY};
    int   ix[4] = {0x7fffffff, 0x7fffffff, 0x7fffffff, 0x7fffffff};
    if (lane < 4) {
        #pragma unroll
        for (int r = 0; r < 4; ++r) {
            v[r]  = cv[(b * 4 + lane) * 4 + r];
            ix[r] = ci[(b * 4 + lane) * 4 + r];
        }
    }
    merge_shfl(v, ix, 1); merge_shfl(v, ix, 2);

    if (lane == 0) {
        float ssum = v[0] + v[1] + v[2] + v[3];   // all positive exp-sums
        #pragma unroll
        for (int r = 0; r < 4; ++r) { fw[r] = v[r] / ssum; fi[r] = ix[r]; }
    }
    __syncthreads();

    const float4* th4 = (const float4*)theta;
    float4* out4 = (float4*)out;
    #pragma unroll
    for (int r = 0; r < 8; ++r) {
        int l = lane + r * 64;        // 0..511
        int j = l >> 7, c4 = l & 127;
        out4[((size_t)b * TOPK + j) * (HD / 4) + c4] = th4[(size_t)fi[j] * (HD / 4) + c4];
    }
    if (lane < TOPK) {
        out[(size_t)BQ * TOPK * HD + b * TOPK + lane]             = mag[fi[lane]];
        out[(size_t)BQ * TOPK * HD + BQ * TOPK + b * TOPK + lane] = fw[lane];
    }
}

template<int KSPLIT>
static void run_pipeline(const float* q, const float* keys, const float* theta,
                         const float* mag, float* out, void* d_ws, hipStream_t stream) {
    float* part = (float*)d_ws;                                  // KSPLIT * 64 * 8192 floats
    float* cv   = part + (size_t)KSPLIT * BQ * N_KEYS;           // 64*4*4 floats
    int*   ci   = (int*)(cv + BQ * 4 * TOPK);                    // 64*4*4 ints

    scores_kernel<KSPLIT><<<dim3(N_KEYS / 64, KSPLIT), 256, 0, stream>>>(q, keys, part);
    topk_partial<KSPLIT><<<BQ * 4, 1024, 0, stream>>>(part, cv, ci);
    finalize_kernel<<<BQ, 64, 0, stream>>>(cv, ci, theta, mag, out);
}

extern "C" void kernel_launch(void* const* d_in, const int* in_sizes, int n_in,
                              void* d_out, int out_size, void* d_ws, size_t ws_size,
                              hipStream_t stream) {
    const float* q     = (const float*)d_in[0];
    const float* keys  = (const float*)d_in[1];
    const float* theta = (const float*)d_in[2];
    const float* mag   = (const float*)d_in[3];
    float* out = (float*)d_out;

    const size_t slice = (size_t)BQ * N_KEYS * sizeof(float);    // 2 MB
    const size_t cand  = (size_t)BQ * 4 * TOPK * 8 + 64;         // candidates + slack

    if      (ws_size >= 8 * slice + cand) run_pipeline<8>(q, keys, theta, mag, out, d_ws, stream);
    else if (ws_size >= 4 * slice + cand) run_pipeline<4>(q, keys, theta, mag, out, d_ws, stream);
    else if (ws_size >= 2 * slice + cand) run_pipeline<2>(q, keys, theta, mag, out, d_ws, stream);
    else                                  run_pipeline<1>(q, keys, theta, mag, out, d_ws, stream);
}

// Round 3
// 34.894 us; speedup vs baseline: 2.1642x; 1.6258x over previous
//
#include <hip/hip_runtime.h>
#include <math.h>

#define N_KEYS 8192
#define DIM    1024
#define BQ     64
#define TOPK   4
#define HD     512
#define KSPLIT 4
#define KSLICE (DIM / KSPLIT)       // 256 dims per k-slice
#define NBLK   128                  // keys per block
#define ROUND_D 64                  // dims staged per round
#define NROUNDS (KSLICE / ROUND_D)  // 4

typedef _Float16 half8 __attribute__((ext_vector_type(8)));
typedef _Float16 half4 __attribute__((ext_vector_type(4)));
typedef float    f32x4 __attribute__((ext_vector_type(4)));

__device__ __forceinline__ bool better(float av, int ai, float bv, int bi) {
    return (av > bv) || (av == bv && ai < bi);
}

__device__ __forceinline__ void ce(float& av, int& ai, float& bv, int& bi) {
    if (!better(av, ai, bv, bi)) {
        float tv = av; av = bv; bv = tv;
        int   ti = ai; ai = bi; bi = ti;
    }
}

__device__ __forceinline__ void merge_shfl(float v[4], int ix[4], int off) {
    float pv[4]; int pi[4];
    #pragma unroll
    for (int r = 0; r < 4; ++r) {
        pv[r] = __shfl_xor(v[r], off);
        pi[r] = __shfl_xor(ix[r], off);
    }
    float nv[4]; int ni[4];
    #pragma unroll
    for (int r = 0; r < 4; ++r) {
        bool ta = better(v[r], ix[r], pv[3 - r], pi[3 - r]);
        nv[r] = ta ? v[r]  : pv[3 - r];
        ni[r] = ta ? ix[r] : pi[3 - r];
    }
    ce(nv[0], ni[0], nv[2], ni[2]);
    ce(nv[1], ni[1], nv[3], ni[3]);
    ce(nv[0], ni[0], nv[1], ni[1]);
    ce(nv[2], ni[2], nv[3], ni[3]);
    #pragma unroll
    for (int r = 0; r < 4; ++r) { v[r] = nv[r]; ix[r] = ni[r]; }
}

// stage one float4 of exp(key) into swizzled hi/lo f16 LDS tiles
__device__ __forceinline__ void stage_write_one(_Float16* BhB, _Float16* BlB,
                                                int t, int r, float4 v) {
    int key = (t >> 4) + 32 * r;          // 0..127
    int k   = 4 * (t & 15);               // 0..60
    float e0 = expf(v.x), e1 = expf(v.y), e2 = expf(v.z), e3 = expf(v.w);
    _Float16 h0 = (_Float16)e0, h1 = (_Float16)e1, h2 = (_Float16)e2, h3 = (_Float16)e3;
    _Float16 l0 = (_Float16)(e0 - (float)h0), l1 = (_Float16)(e1 - (float)h1);
    _Float16 l2 = (_Float16)(e2 - (float)h2), l3 = (_Float16)(e3 - (float)h3);
    int g    = (k >> 3) ^ (key & 7);      // XOR swizzle on 16B groups
    int hidx = key * 64 + g * 8 + (k & 7);
    half4 hv; hv[0] = h0; hv[1] = h1; hv[2] = h2; hv[3] = h3;
    half4 lv; lv[0] = l0; lv[1] = l1; lv[2] = l2; lv[3] = l3;
    *(half4*)(BhB + hidx) = hv;
    *(half4*)(BlB + hidx) = lv;
}

// ---------------- scores: split-f16 3-MFMA emulated-f32 GEMM ----------------
// part[slice][b][key] = sum_{d in slice} exp(q[b,d]) * exp(k[key,d])
__global__ __launch_bounds__(512, 2) void scores_mfma(const float* __restrict__ q,
                                                      const float* __restrict__ keys,
                                                      float* __restrict__ part) {
    __shared__ _Float16 Bh[2][NBLK * ROUND_D];   // 16 KB each buf
    __shared__ _Float16 Bl[2][NBLK * ROUND_D];

    const int t    = threadIdx.x;
    const int lane = t & 63, w = t >> 6;
    const int wm = w >> 2, wn = w & 3;           // 2(M) x 4(N) wave grid
    const int l15 = lane & 15, l4 = lane >> 4;
    const int i0    = blockIdx.x * NBLK;
    const int dbase = blockIdx.y * KSLICE;

    // ---- prologue: issue stage-0 key loads ----
    const int skey = t >> 4, sc4 = t & 15;
    float4 s0, s1, s2, s3;
    {
        const float* kb = keys + (size_t)i0 * DIM + dbase + 4 * sc4;
        s0 = *(const float4*)(kb + (size_t)(skey     ) * DIM);
        s1 = *(const float4*)(kb + (size_t)(skey + 32) * DIM);
        s2 = *(const float4*)(kb + (size_t)(skey + 64) * DIM);
        s3 = *(const float4*)(kb + (size_t)(skey + 96) * DIM);
    }

    // ---- build A fragments in registers (exp(q) hi/lo f16) ----
    // lane holds A[row = 32*wm + 16*mt + l15][k = 32*ks + l4*8 + j]
    half8 Ah[8][2], Al[8][2];
    #pragma unroll
    for (int ks = 0; ks < 8; ++ks) {
        #pragma unroll
        for (int mt = 0; mt < 2; ++mt) {
            int row = 32 * wm + 16 * mt + l15;
            int d   = dbase + 32 * ks + l4 * 8;
            const float4* p = (const float4*)&q[(size_t)row * DIM + d];
            float4 x0 = p[0], x1 = p[1];
            float e[8] = {expf(x0.x), expf(x0.y), expf(x0.z), expf(x0.w),
                          expf(x1.x), expf(x1.y), expf(x1.z), expf(x1.w)};
            half8 h, l;
            #pragma unroll
            for (int j = 0; j < 8; ++j) {
                h[j] = (_Float16)e[j];
                l[j] = (_Float16)(e[j] - (float)h[j]);
            }
            Ah[ks][mt] = h;
            Al[ks][mt] = l;
        }
    }

    // ---- write stage 0 ----
    stage_write_one(Bh[0], Bl[0], t, 0, s0);
    stage_write_one(Bh[0], Bl[0], t, 1, s1);
    stage_write_one(Bh[0], Bl[0], t, 2, s2);
    stage_write_one(Bh[0], Bl[0], t, 3, s3);
    __syncthreads();

    f32x4 acc[2][2];
    #pragma unroll
    for (int mt = 0; mt < 2; ++mt)
        #pragma unroll
        for (int nt = 0; nt < 2; ++nt)
            #pragma unroll
            for (int r = 0; r < 4; ++r) acc[mt][nt][r] = 0.f;

    for (int rnd = 0; rnd < NROUNDS; ++rnd) {
        const int buf = rnd & 1;
        // issue next round's key loads early (hide HBM under MFMA)
        float4 n0, n1, n2, n3;
        if (rnd + 1 < NROUNDS) {
            const float* kb = keys + (size_t)i0 * DIM + dbase + (rnd + 1) * ROUND_D + 4 * sc4;
            n0 = *(const float4*)(kb + (size_t)(skey     ) * DIM);
            n1 = *(const float4*)(kb + (size_t)(skey + 32) * DIM);
            n2 = *(const float4*)(kb + (size_t)(skey + 64) * DIM);
            n3 = *(const float4*)(kb + (size_t)(skey + 96) * DIM);
        }
        // compute on buf
        #pragma unroll
        for (int sub = 0; sub < 2; ++sub) {
            const int ks = rnd * 2 + sub;
            half8 bh[2], bl[2];
            #pragma unroll
            for (int nt = 0; nt < 2; ++nt) {
                int key  = 32 * wn + 16 * nt + l15;
                int g    = (4 * sub + l4) ^ (key & 7);
                int hidx = key * 64 + g * 8;
                bh[nt] = *(const half8*)&Bh[buf][hidx];
                bl[nt] = *(const half8*)&Bl[buf][hidx];
            }
            #pragma unroll
            for (int mt = 0; mt < 2; ++mt)
                #pragma unroll
                for (int nt = 0; nt < 2; ++nt) {
                    acc[mt][nt] = __builtin_amdgcn_mfma_f32_16x16x32_f16(Ah[ks][mt], bh[nt], acc[mt][nt], 0, 0, 0);
                    acc[mt][nt] = __builtin_amdgcn_mfma_f32_16x16x32_f16(Ah[ks][mt], bl[nt], acc[mt][nt], 0, 0, 0);
                    acc[mt][nt] = __builtin_amdgcn_mfma_f32_16x16x32_f16(Al[ks][mt], bh[nt], acc[mt][nt], 0, 0, 0);
                }
        }
        // write next round's tiles into the other buffer
        if (rnd + 1 < NROUNDS) {
            stage_write_one(Bh[buf ^ 1], Bl[buf ^ 1], t, 0, n0);
            stage_write_one(Bh[buf ^ 1], Bl[buf ^ 1], t, 1, n1);
            stage_write_one(Bh[buf ^ 1], Bl[buf ^ 1], t, 2, n2);
            stage_write_one(Bh[buf ^ 1], Bl[buf ^ 1], t, 3, n3);
        }
        __syncthreads();
    }

    // ---- epilogue: C layout col=lane&15, row=(lane>>4)*4+reg ----
    float* pb = part + (size_t)blockIdx.y * (BQ * N_KEYS);
    #pragma unroll
    for (int mt = 0; mt < 2; ++mt)
        #pragma unroll
        for (int nt = 0; nt < 2; ++nt)
            #pragma unroll
            for (int r = 0; r < 4; ++r) {
                int row = 32 * wm + 16 * mt + l4 * 4 + r;
                int col = i0 + 32 * wn + 16 * nt + l15;
                pb[(size_t)row * N_KEYS + col] = acc[mt][nt][r];
            }
}

// ---------------- topk partial: per (b, quarter-of-keys) sorted top-4 ----------------
template<int KS>
__global__ __launch_bounds__(1024) void topk_partial(const float* __restrict__ part,
                                                     float* __restrict__ cv,
                                                     int* __restrict__ ci) {
    const int b     = blockIdx.x >> 2;
    const int chunk = blockIdx.x & 3;
    const int t     = threadIdx.x;
    const int lane  = t & 63, wid = t >> 6;

    __shared__ float sv[16][4];
    __shared__ int   si[16][4];

    float v[4]  = {-INFINITY, -INFINITY, -INFINITY, -INFINITY};
    int   ix[4] = {0x7fffffff, 0x7fffffff, 0x7fffffff, 0x7fffffff};

    const float* pb = part + (size_t)b * N_KEYS;
    #pragma unroll
    for (int r = 0; r < 2; ++r) {
        int i = chunk * 2048 + t + r * 1024;
        float s = 0.f;
        #pragma unroll
        for (int sl = 0; sl < KS; ++sl)
            s += pb[(size_t)sl * (BQ * N_KEYS) + i];
        if (better(s, i, v[3], ix[3])) {
            v[3] = s; ix[3] = i;
            #pragma unroll
            for (int p = 3; p > 0; --p) {
                if (better(v[p], ix[p], v[p - 1], ix[p - 1])) {
                    float tv = v[p]; v[p] = v[p-1]; v[p-1] = tv;
                    int   ti = ix[p]; ix[p] = ix[p-1]; ix[p-1] = ti;
                }
            }
        }
    }
    merge_shfl(v, ix, 1);  merge_shfl(v, ix, 2);  merge_shfl(v, ix, 4);
    merge_shfl(v, ix, 8);  merge_shfl(v, ix, 16); merge_shfl(v, ix, 32);

    if (lane == 0) {
        #pragma unroll
        for (int r = 0; r < 4; ++r) { sv[wid][r] = v[r]; si[wid][r] = ix[r]; }
    }
    __syncthreads();

    if (wid == 0) {
        float mv[4]; int mi[4];
        if (lane < 16) {
            #pragma unroll
            for (int r = 0; r < 4; ++r) { mv[r] = sv[lane][r]; mi[r] = si[lane][r]; }
        } else {
            #pragma unroll
            for (int r = 0; r < 4; ++r) { mv[r] = -INFINITY; mi[r] = 0x7fffffff; }
        }
        merge_shfl(mv, mi, 1); merge_shfl(mv, mi, 2);
        merge_shfl(mv, mi, 4); merge_shfl(mv, mi, 8);
        if (lane == 0) {
            #pragma unroll
            for (int r = 0; r < 4; ++r) {
                cv[blockIdx.x * 4 + r] = mv[r];
                ci[blockIdx.x * 4 + r] = mi[r];
            }
        }
    }
}

// ---------------- finalize: merge 4 chunk-lists, softmax, gather ----------------
__global__ __launch_bounds__(64) void finalize_kernel(const float* __restrict__ cv,
                                                      const int* __restrict__ ci,
                                                      const float* __restrict__ theta,
                                                      const float* __restrict__ mag,
                                                      float* __restrict__ out) {
    const int b    = blockIdx.x;
    const int lane = threadIdx.x;   // 64

    __shared__ float fw[4];
    __shared__ int   fi[4];

    float v[4]  = {-INFINITY, -INFINITY, -INFINITY, -INFINITY};
    int   ix[4] = {0x7fffffff, 0x7fffffff, 0x7fffffff, 0x7fffffff};
    if (lane < 4) {
        #pragma unroll
        for (int r = 0; r < 4; ++r) {
            v[r]  = cv[(b * 4 + lane) * 4 + r];
            ix[r] = ci[(b * 4 + lane) * 4 + r];
        }
    }
    merge_shfl(v, ix, 1); merge_shfl(v, ix, 2);

    if (lane == 0) {
        float ssum = v[0] + v[1] + v[2] + v[3];   // positive exp-sums
        #pragma unroll
        for (int r = 0; r < 4; ++r) { fw[r] = v[r] / ssum; fi[r] = ix[r]; }
    }
    __syncthreads();

    const float4* th4 = (const float4*)theta;
    float4* out4 = (float4*)out;
    #pragma unroll
    for (int r = 0; r < 8; ++r) {
        int l = lane + r * 64;
        int j = l >> 7, c4 = l & 127;
        out4[((size_t)b * TOPK + j) * (HD / 4) + c4] = th4[(size_t)fi[j] * (HD / 4) + c4];
    }
    if (lane < TOPK) {
        out[(size_t)BQ * TOPK * HD + b * TOPK + lane]             = mag[fi[lane]];
        out[(size_t)BQ * TOPK * HD + BQ * TOPK + b * TOPK + lane] = fw[lane];
    }
}

extern "C" void kernel_launch(void* const* d_in, const int* in_sizes, int n_in,
                              void* d_out, int out_size, void* d_ws, size_t ws_size,
                              hipStream_t stream) {
    const float* q     = (const float*)d_in[0];
    const float* keys  = (const float*)d_in[1];
    const float* theta = (const float*)d_in[2];
    const float* mag   = (const float*)d_in[3];
    float* out = (float*)d_out;

    float* part = (float*)d_ws;                               // 4 * 64*8192 f32 = 8 MB
    float* cv   = part + (size_t)KSPLIT * BQ * N_KEYS;
    int*   ci   = (int*)(cv + BQ * 4 * TOPK);

    scores_mfma<<<dim3(N_KEYS / NBLK, KSPLIT), 512, 0, stream>>>(q, keys, part);
    topk_partial<KSPLIT><<<BQ * 4, 1024, 0, stream>>>(part, cv, ci);
    finalize_kernel<<<BQ, 64, 0, stream>>>(cv, ci, theta, mag, out);
}